// Round 2
// baseline (971.659 us; speedup 1.0000x reference)
//
#include <hip/hip_runtime.h>

#define DIM 64
#define NG 8
#define SCAN_B 1024
#define EPT 8   // edges per thread in hist/bin kernels (tile = 256*EPT = 2048)

typedef unsigned int uint;
typedef unsigned short ushort;

// ---- bf16 helpers ----
__device__ __forceinline__ float bf16_lo(uint u) {
    union { uint u; float f; } c; c.u = u << 16; return c.f;
}
__device__ __forceinline__ float bf16_hi(uint u) {
    union { uint u; float f; } c; c.u = u & 0xffff0000u; return c.f;
}
__device__ __forceinline__ uint f2b(float f) {   // bf16 in low 16 bits (RNE)
    union { float f; uint u; } c; c.f = f;
    return (c.u + 0x7fffu + ((c.u >> 16) & 1u)) >> 16;
}

// f32 -> bf16, 8 elems/thread, output row pitch/offset in ushorts (rows of 64).
__global__ void cvt_bf16_pitch(const float* __restrict__ in, ushort* __restrict__ out,
                               int n8, int pitch, int off) {
    int k = blockIdx.x * blockDim.x + threadIdx.x;
    if (k >= n8) return;
    int row = k >> 3, g = k & 7;
    const float4* p = (const float4*)in + (size_t)k * 2;
    float4 a = p[0], b = p[1];
    uint4 o;
    o.x = f2b(a.x) | (f2b(a.y) << 16);
    o.y = f2b(a.z) | (f2b(a.w) << 16);
    o.z = f2b(b.x) | (f2b(b.y) << 16);
    o.w = f2b(b.z) | (f2b(b.w) << 16);
    *(uint4*)(out + (size_t)row * pitch + off + g * 8) = o;
}

// ---- CSR build ----
// Per-node degree histogram + per-group (16-bucket) edge counts.
// Normal (cached) loads: bin_edges re-reads src/dst right after -> L3 hits.
__global__ __launch_bounds__(256) void edge_hist(
        const int* __restrict__ src, const int* __restrict__ dst,
        int* __restrict__ deg, int* __restrict__ gcnt,
        int n_users, int E, int uchunk, int ichunk) {
    __shared__ int h[16];
    if (threadIdx.x < 16) h[threadIdx.x] = 0;
    __syncthreads();
    int t0 = blockIdx.x * (256 * EPT) + threadIdx.x;
    #pragma unroll
    for (int k = 0; k < EPT; ++k) {
        int e = t0 + k * 256;
        if (e < E) {
            int s = src[e], t = dst[e];
            atomicAdd(&deg[s], 1);
            atomicAdd(&deg[n_users + t], 1);
            atomicAdd(&h[s / uchunk], 1);
            atomicAdd(&h[8 + t / ichunk], 1);
        }
    }
    __syncthreads();
    if (threadIdx.x < 16) {
        int v = h[threadIdx.x];
        if (v) atomicAdd(&gcnt[threadIdx.x], v);
    }
}

// Tiny exclusive scan of the 16 bucket counts -> bucket bases.
__global__ void scan16(const int* __restrict__ gcnt, int* __restrict__ cursor,
                       int* __restrict__ bstart) {
    if (threadIdx.x == 0) {
        int run = 0;
        for (int b = 0; b < 16; ++b) {
            bstart[b] = run;
            cursor[b] = run;
            run += gcnt[b];
        }
        bstart[16] = run;   // == 2E
    }
}

// Phase 1: single read of the edge list; scatter each edge into its user-group
// bucket and item-group bucket as ONE packed u32.
//   user word: s_local | (t << 15)   (uchunk=25000 < 2^15, t < 2^17)
//   item word: t_local | (s << 14)   (ichunk=12500 < 2^14, s < 2^18)
// LDS per-tile counters + one global cursor atomicAdd per bucket per tile make
// the bucket writes dense ~1KB chunks (no write amplification).
__global__ __launch_bounds__(256) void bin_edges(
        const int* __restrict__ src, const int* __restrict__ dst,
        int* __restrict__ cursor, uint* __restrict__ bins,
        int E, int uchunk, int ichunk) {
    __shared__ int cnt[16];
    __shared__ int base[16];
    if (threadIdx.x < 16) cnt[threadIdx.x] = 0;
    __syncthreads();
    int t0 = blockIdx.x * (256 * EPT) + threadIdx.x;
    int s[EPT], t[EPT], bu[EPT], bi[EPT], ou[EPT], oi[EPT];
    #pragma unroll
    for (int k = 0; k < EPT; ++k) {
        int e = t0 + k * 256;
        if (e < E) {
            s[k] = src[e]; t[k] = dst[e];
            bu[k] = s[k] / uchunk;
            bi[k] = t[k] / ichunk;
            ou[k] = atomicAdd(&cnt[bu[k]], 1);
            oi[k] = atomicAdd(&cnt[8 + bi[k]], 1);
        }
    }
    __syncthreads();
    if (threadIdx.x < 16)
        base[threadIdx.x] = atomicAdd(&cursor[threadIdx.x], cnt[threadIdx.x]);
    __syncthreads();
    #pragma unroll
    for (int k = 0; k < EPT; ++k) {
        int e = t0 + k * 256;
        if (e < E) {
            uint wu = (uint)(s[k] - bu[k] * uchunk) | ((uint)t[k] << 15);
            uint wi = (uint)(t[k] - bi[k] * ichunk) | ((uint)s[k] << 14);
            __builtin_nontemporal_store(wu, &bins[base[bu[k]] + ou[k]]);
            __builtin_nontemporal_store(wi, &bins[base[8 + bi[k]] + oi[k]]);
        }
    }
}

// Phase 2: per-bucket CSR fill. bucket = blockIdx & 15 -> under round-robin
// dispatch, all blocks of bucket b land on XCD (b&7), so the scattered col
// writes stay confined to a ~1.5 MB slice in ONE XCD's L2 with only a 1.5 MB
// nt streaming read competing for it -> dirty lines fill fully before evict.
__global__ __launch_bounds__(256) void fill_bins(
        const uint* __restrict__ bins, const int* __restrict__ bstart,
        int* __restrict__ deg, int* __restrict__ col,
        int n_users, int uchunk, int ichunk) {
    int b    = blockIdx.x & 15;
    int bi   = blockIdx.x >> 4;
    int bpb  = gridDim.x >> 4;
    int nthr = bpb * 256;
    int tid  = bi * 256 + threadIdx.x;
    int lo = bstart[b], hi = bstart[b + 1];
    if (b < 8) {
        int ulo = b * uchunk;
        for (int idx = lo + tid; idx < hi; idx += nthr) {
            uint w = __builtin_nontemporal_load(&bins[idx]);
            int s = ulo + (int)(w & 32767u);
            int t = (int)(w >> 15);
            col[atomicAdd(&deg[s], 1)] = t;
        }
    } else {
        int ilo = (b - 8) * ichunk;
        for (int idx = lo + tid; idx < hi; idx += nthr) {
            uint w = __builtin_nontemporal_load(&bins[idx]);
            int t = ilo + (int)(w & 16383u);
            int s = (int)(w >> 14);
            col[atomicAdd(&deg[n_users + t], 1)] = s;
        }
    }
}

__global__ void scan1(int* __restrict__ a, int* __restrict__ bsum, int n) {
    __shared__ int ws[16];
    int i = blockIdx.x * SCAN_B + threadIdx.x;
    int lane = threadIdx.x & 63, wid = threadIdx.x >> 6;
    int v = (i < n) ? a[i] : 0;
    int incl = v;
    #pragma unroll
    for (int off = 1; off < 64; off <<= 1) {
        int t = __shfl_up(incl, off, 64);
        if (lane >= off) incl += t;
    }
    if (lane == 63) ws[wid] = incl;
    __syncthreads();
    int woff = 0;
    for (int w = 0; w < wid; ++w) woff += ws[w];
    if (i < n) a[i] = woff + incl - v;
    if (threadIdx.x == SCAN_B - 1) bsum[blockIdx.x] = woff + incl;
}

__global__ void scan2(int* __restrict__ bsum, int nb) {
    __shared__ int ws[16];
    int lane = threadIdx.x & 63, wid = threadIdx.x >> 6;
    int v = ((int)threadIdx.x < nb) ? bsum[threadIdx.x] : 0;
    int incl = v;
    #pragma unroll
    for (int off = 1; off < 64; off <<= 1) {
        int t = __shfl_up(incl, off, 64);
        if (lane >= off) incl += t;
    }
    if (lane == 63) ws[wid] = incl;
    __syncthreads();
    int woff = 0;
    for (int w = 0; w < wid; ++w) woff += ws[w];
    if ((int)threadIdx.x < nb) bsum[threadIdx.x] = woff + incl - v;
}

__global__ void scan3(int* __restrict__ cur, const int* __restrict__ bsum, int n) {
    int i = blockIdx.x * SCAN_B + threadIdx.x;
    if (i < n) cur[i] += bsum[blockIdx.x];
}

// ---- 128B-row gather (one wave per node; r=lane>>3 row slot, c=lane&7 chunk).
// ends[-1] must be valid (sentinel). COMBINE=0: bf16 out at (ob_pitch, ob_off).
// COMBINE=1: outf = (x0 + x1 + mean)/3, x1 bf16 at (x1_pitch, x1_off).
// NOTE: outf may alias x1's buffer (same row, same wave) — data dependency
// (store value uses loaded x1) keeps this safe; no __restrict__ on those.
template <int COMBINE>
__global__ __launch_bounds__(256) void gather128(
        const ushort* __restrict__ feat,
        const int* __restrict__ ends,
        const int* __restrict__ col,
        const float* __restrict__ x0,
        const ushort* x1, int x1_pitch, int x1_off,
        float* outf,
        ushort* outb, int ob_pitch, int ob_off,
        int n) {
    int node = blockIdx.x * 4 + (threadIdx.x >> 6);
    if (node >= n) return;
    int lane = threadIdx.x & 63;
    int r = lane >> 3, c = lane & 7;
    int beg = ends[node - 1];
    int end = ends[node];
    const ushort* fbase = feat + c * 8;

    float acc[8];
    #pragma unroll
    for (int j = 0; j < 8; ++j) acc[j] = 0.0f;

    for (int e = beg; e < end; e += 16) {
        int i0 = e + r, i1 = e + 8 + r;
        bool ok0 = i0 < end, ok1 = i1 < end;
        int nb0 = col[ok0 ? i0 : beg];
        int nb1 = col[ok1 ? i1 : beg];
        uint4 v0 = *(const uint4*)(fbase + (size_t)nb0 * DIM);
        uint4 v1 = *(const uint4*)(fbase + (size_t)nb1 * DIM);
        if (ok0) {
            acc[0] += bf16_lo(v0.x); acc[1] += bf16_hi(v0.x);
            acc[2] += bf16_lo(v0.y); acc[3] += bf16_hi(v0.y);
            acc[4] += bf16_lo(v0.z); acc[5] += bf16_hi(v0.z);
            acc[6] += bf16_lo(v0.w); acc[7] += bf16_hi(v0.w);
        }
        if (ok1) {
            acc[0] += bf16_lo(v1.x); acc[1] += bf16_hi(v1.x);
            acc[2] += bf16_lo(v1.y); acc[3] += bf16_hi(v1.y);
            acc[4] += bf16_lo(v1.z); acc[5] += bf16_hi(v1.z);
            acc[6] += bf16_lo(v1.w); acc[7] += bf16_hi(v1.w);
        }
    }
    #pragma unroll
    for (int m = 8; m < 64; m <<= 1) {
        #pragma unroll
        for (int j = 0; j < 8; ++j) acc[j] += __shfl_xor(acc[j], m, 64);
    }
    if (r == 0) {
        int d = end - beg;
        float inv = (d > 0) ? 1.0f / (float)d : 0.0f;
        if (COMBINE) {
            size_t base = (size_t)node * DIM + c * 8;
            float4 xa = *(const float4*)(x0 + base);
            float4 xb = *(const float4*)(x0 + base + 4);
            uint4  xq = *(const uint4*)(x1 + (size_t)node * x1_pitch + x1_off + c * 8);
            float4 oa, ob;
            oa.x = (xa.x + bf16_lo(xq.x) + acc[0] * inv) * (1.0f / 3.0f);
            oa.y = (xa.y + bf16_hi(xq.x) + acc[1] * inv) * (1.0f / 3.0f);
            oa.z = (xa.z + bf16_lo(xq.y) + acc[2] * inv) * (1.0f / 3.0f);
            oa.w = (xa.w + bf16_hi(xq.y) + acc[3] * inv) * (1.0f / 3.0f);
            ob.x = (xb.x + bf16_lo(xq.z) + acc[4] * inv) * (1.0f / 3.0f);
            ob.y = (xb.y + bf16_hi(xq.z) + acc[5] * inv) * (1.0f / 3.0f);
            ob.z = (xb.z + bf16_lo(xq.w) + acc[6] * inv) * (1.0f / 3.0f);
            ob.w = (xb.w + bf16_hi(xq.w) + acc[7] * inv) * (1.0f / 3.0f);
            *(float4*)(outf + base)     = oa;
            *(float4*)(outf + base + 4) = ob;
        } else {
            uint4 o;
            o.x = f2b(acc[0] * inv) | (f2b(acc[1] * inv) << 16);
            o.y = f2b(acc[2] * inv) | (f2b(acc[3] * inv) << 16);
            o.z = f2b(acc[4] * inv) | (f2b(acc[5] * inv) << 16);
            o.w = f2b(acc[6] * inv) | (f2b(acc[7] * inv) << 16);
            *(uint4*)(outb + (size_t)node * ob_pitch + ob_off + c * 8) = o;
        }
    }
}

// ---- 256B-row fused item pass: feat = u01 (u0|u1 interleaved, pitch 128).
// Computes i1 = mean(u0-nbrs), i2 = mean(u1-nbrs) in ONE col walk.
// outf = (x0 + i1 + i2)/3 (f32), outb = bf16(i1) (dense pitch 64).
__global__ __launch_bounds__(256) void gather256_combine(
        const ushort* __restrict__ feat,
        const int* __restrict__ ends,
        const int* __restrict__ col,
        const float* __restrict__ x0,
        float* __restrict__ outf,
        ushort* __restrict__ outb,
        int n) {
    int node = blockIdx.x * 4 + (threadIdx.x >> 6);
    if (node >= n) return;
    int lane = threadIdx.x & 63;
    int c = lane & 15, r = lane >> 4;          // c: 16B chunk of 256B row
    int beg = ends[node - 1];
    int end = ends[node];
    const ushort* fbase = feat + c * 8;

    float acc[8];
    #pragma unroll
    for (int j = 0; j < 8; ++j) acc[j] = 0.0f;

    for (int e = beg; e < end; e += 8) {
        int i0 = e + r, i1 = e + 4 + r;
        bool ok0 = i0 < end, ok1 = i1 < end;
        int nb0 = col[ok0 ? i0 : beg];
        int nb1 = col[ok1 ? i1 : beg];
        uint4 v0 = *(const uint4*)(fbase + (size_t)nb0 * 128);
        uint4 v1 = *(const uint4*)(fbase + (size_t)nb1 * 128);
        if (ok0) {
            acc[0] += bf16_lo(v0.x); acc[1] += bf16_hi(v0.x);
            acc[2] += bf16_lo(v0.y); acc[3] += bf16_hi(v0.y);
            acc[4] += bf16_lo(v0.z); acc[5] += bf16_hi(v0.z);
            acc[6] += bf16_lo(v0.w); acc[7] += bf16_hi(v0.w);
        }
        if (ok1) {
            acc[0] += bf16_lo(v1.x); acc[1] += bf16_hi(v1.x);
            acc[2] += bf16_lo(v1.y); acc[3] += bf16_hi(v1.y);
            acc[4] += bf16_lo(v1.z); acc[5] += bf16_hi(v1.z);
            acc[6] += bf16_lo(v1.w); acc[7] += bf16_hi(v1.w);
        }
    }
    // fold the 4 r-slots (lane bits 4,5)
    #pragma unroll
    for (int m = 16; m < 64; m <<= 1) {
        #pragma unroll
        for (int j = 0; j < 8; ++j) acc[j] += __shfl_xor(acc[j], m, 64);
    }
    // partner exchange: lane c (<8, u0-part) pairs with lane c+8 (u1-part, same elems)
    float b8[8];
    #pragma unroll
    for (int j = 0; j < 8; ++j) b8[j] = __shfl_xor(acc[j], 8, 64);

    if (r == 0 && c < 8) {
        int d = end - beg;
        float inv = (d > 0) ? 1.0f / (float)d : 0.0f;
        size_t base = (size_t)node * DIM + c * 8;
        float4 xa = *(const float4*)(x0 + base);
        float4 xb = *(const float4*)(x0 + base + 4);
        float i1v[8];
        #pragma unroll
        for (int j = 0; j < 8; ++j) i1v[j] = acc[j] * inv;
        float4 oa, ob;
        oa.x = (xa.x + i1v[0] + b8[0] * inv) * (1.0f / 3.0f);
        oa.y = (xa.y + i1v[1] + b8[1] * inv) * (1.0f / 3.0f);
        oa.z = (xa.z + i1v[2] + b8[2] * inv) * (1.0f / 3.0f);
        oa.w = (xa.w + i1v[3] + b8[3] * inv) * (1.0f / 3.0f);
        ob.x = (xb.x + i1v[4] + b8[4] * inv) * (1.0f / 3.0f);
        ob.y = (xb.y + i1v[5] + b8[5] * inv) * (1.0f / 3.0f);
        ob.z = (xb.z + i1v[6] + b8[6] * inv) * (1.0f / 3.0f);
        ob.w = (xb.w + i1v[7] + b8[7] * inv) * (1.0f / 3.0f);
        *(float4*)(outf + base)     = oa;
        *(float4*)(outf + base + 4) = ob;
        uint4 q;
        q.x = f2b(i1v[0]) | (f2b(i1v[1]) << 16);
        q.y = f2b(i1v[2]) | (f2b(i1v[3]) << 16);
        q.z = f2b(i1v[4]) | (f2b(i1v[5]) << 16);
        q.w = f2b(i1v[6]) | (f2b(i1v[7]) << 16);
        *(uint4*)(outb + base) = q;
    }
}

extern "C" void kernel_launch(void* const* d_in, const int* in_sizes, int n_in,
                              void* d_out, int out_size, void* d_ws, size_t ws_size,
                              hipStream_t stream) {
    const float* u0  = (const float*)d_in[0];
    const float* i0  = (const float*)d_in[1];
    const int*   src = (const int*)d_in[2];
    const int*   dst = (const int*)d_in[3];

    const int n_users = in_sizes[0] / DIM;   // 200000
    const int n_items = in_sizes[1] / DIM;   // 100000
    const int E       = in_sizes[2];         // 3000000
    const int n_nodes = n_users + n_items;
    const int uchunk  = (n_users + NG - 1) / NG;   // 25000 (< 2^15: packing req)
    const int ichunk  = (n_items + NG - 1) / NG;   // 12500 (< 2^14: packing req)

    const size_t u_elems = (size_t)n_users * DIM;
    const size_t i_elems = (size_t)n_items * DIM;

    // Workspace (~38 MB):
    //   cur_full[n_nodes+1] | gcnt[16] cursor[16] bstart[17] pad[3] | col[2E]
    //   | bsum[1024] | ib[i_elems bf16]
    int* cur_full = (int*)d_ws;       // [0] = 0 sentinel, deg = cur_full+1
    int* deg    = cur_full + 1;
    int* gcnt   = cur_full + (n_nodes + 1);
    int* cursor = gcnt + 16;
    int* bstart = cursor + 16;        // 17 ints + 3 pad
    int* col    = bstart + 20;
    int* bsum   = col + 2 * (size_t)E;
    ushort* ib  = (ushort*)(bsum + 1024);  // holds i0 bf16, later overwritten by i1 bf16

    // d_out: user region doubles as u01 (u0|u1 interleaved bf16, 256B rows).
    // item region (out_i, 25.6 MB) doubles as the packed-edge bin array (24 MB)
    // during CSR build — dead until gather256_combine writes it.
    float* out_u = (float*)d_out;
    float* out_i = out_u + u_elems;
    ushort* u01  = (ushort*)d_out;         // exactly overlays out_u (51.2 MB)
    uint*  bins  = (uint*)out_i;

    const int BLK = 256;
    const int nb = (n_nodes + SCAN_B - 1) / SCAN_B;
    const int etiles = (E + BLK * EPT - 1) / (BLK * EPT);

    // ---- CSR build: hist(+group counts) -> scan16 -> bin -> node scans -> fill
    hipMemsetAsync(cur_full, 0, (size_t)(n_nodes + 1 + 16) * sizeof(int), stream);
    edge_hist<<<etiles, BLK, 0, stream>>>(src, dst, deg, gcnt, n_users, E, uchunk, ichunk);
    scan16<<<1, 64, 0, stream>>>(gcnt, cursor, bstart);
    bin_edges<<<etiles, BLK, 0, stream>>>(src, dst, cursor, bins, E, uchunk, ichunk);
    scan1<<<nb, SCAN_B, 0, stream>>>(deg, bsum, n_nodes);
    scan2<<<1, SCAN_B, 0, stream>>>(bsum, nb);
    scan3<<<nb, SCAN_B, 0, stream>>>(deg, bsum, n_nodes);
    fill_bins<<<16 * 128, BLK, 0, stream>>>(bins, bstart, deg, col, n_users, uchunk, ichunk);
    // deg now holds inclusive segment ends (users: [0..), items at deg+n_users).

    // ---- stage bf16 (after fill: bins region is dead from here on) ----
    cvt_bf16_pitch<<<(int)((u_elems / 8 + BLK - 1) / BLK), BLK, 0, stream>>>(
        u0, u01, (int)(u_elems / 8), 128, 0);
    cvt_bf16_pitch<<<(int)((i_elems / 8 + BLK - 1) / BLK), BLK, 0, stream>>>(
        i0, ib, (int)(i_elems / 8), 64, 0);

    const int ug = (n_users + 3) / 4;
    const int ig = (n_items + 3) / 4;

    // ---- Pass A: u1 = mean(i0-nbrs) -> u01 odd halves (bf16) ----
    gather128<0><<<ug, BLK, 0, stream>>>(ib, deg, col, nullptr,
                                         nullptr, 0, 0, nullptr,
                                         u01, 128, 64, n_users);

    // ---- Pass C: fused item pass: out_i = (i0 + i1 + i2)/3, ib <- bf16(i1) ----
    gather256_combine<<<ig, BLK, 0, stream>>>(u01, deg + n_users, col,
                                              i0, out_i, ib, n_items);

    // ---- Pass D: out_u = (u0 + u1 + mean(i1-nbrs))/3 (u1 from u01 odd) ----
    gather128<1><<<ug, BLK, 0, stream>>>(ib, deg, col, u0,
                                         u01, 128, 64, out_u,
                                         nullptr, 0, 0, n_users);
}